// Round 1
// baseline (402.440 us; speedup 1.0000x reference)
//
#include <hip/hip_runtime.h>
#include <math.h>

#define N_ATOMS 10000
#define N_PAIRS 160000
#define FDIM 256
#define GDIM 16
#define HDIM 64
#define HIDDIM 256
#define MLP_IN 640
#define MLP_OUT 258

__device__ __forceinline__ float gelu_exact(float x) {
    return 0.5f * x * (1.0f + erff(x * 0.70710678118654752f));
}

// ---------------------------------------------------------------------------
// Scatter: Gs_sum[i,g]  += gs[p,g]   (16 floats/pair)
//          GV_sum[i,d,g]+= gv[p,d,g] (48 floats/pair)
// One thread per (pair, element-of-64).
// ---------------------------------------------------------------------------
__global__ void scatter_kernel(const int* __restrict__ idx_j,
                               const float* __restrict__ gs,
                               const float* __restrict__ gv,
                               float* __restrict__ Gs_sum,
                               float* __restrict__ GV_sum) {
    long long tid = (long long)blockIdx.x * blockDim.x + threadIdx.x;
    if (tid >= (long long)N_PAIRS * 64) return;
    int p = (int)(tid >> 6);
    int e = (int)(tid & 63);
    int i = idx_j[p];
    if (e < GDIM) {
        atomicAdd(&Gs_sum[i * GDIM + e], gs[p * GDIM + e]);
    } else {
        int e2 = e - GDIM;
        atomicAdd(&GV_sum[i * 48 + e2], gv[p * 48 + e2]);
    }
}

// ---------------------------------------------------------------------------
// Build "combined" (N x 640): [radial_emb(256) | vector_emb(64) | radial_q(256) | 0(64)]
//   S[f]          = sum_g Gs_sum[i,g] * W_gs[f,g]
//   radial_emb[f] = emb[i,f] * S[f]
//   radial_q[f]   = q[i]     * S[f]
//   vector_emb[h] = || sum_g M[i,g,h] * GV_sum[i,:,g] ||_2   (over d=0..2)
// One block (256 threads) per atom.
// ---------------------------------------------------------------------------
__global__ void build_combined(const float* __restrict__ emb,
                               const float* __restrict__ q,
                               const float* __restrict__ W_gs,
                               const float* __restrict__ Gs_sum,
                               const float* __restrict__ GV_sum,
                               const float* __restrict__ Mmat,
                               float* __restrict__ combined) {
    __shared__ float sW[FDIM * 17];   // W_gs, padded stride 17 to kill bank conflicts
    __shared__ float sG[GDIM];
    __shared__ float sGV[48];
    int i = blockIdx.x;
    int t = threadIdx.x;  // 0..255

    for (int j = t; j < FDIM * GDIM; j += 256) {
        int f = j >> 4, g = j & 15;
        sW[f * 17 + g] = W_gs[j];
    }
    if (t < GDIM) sG[t] = Gs_sum[i * GDIM + t];
    if (t < 48)  sGV[t] = GV_sum[i * 48 + t];
    __syncthreads();

    float S = 0.f;
#pragma unroll
    for (int g = 0; g < GDIM; ++g) S += sG[g] * sW[t * 17 + g];

    float e  = emb[(long long)i * FDIM + t];
    float qq = q[i];
    float* crow = combined + (long long)i * MLP_IN;
    crow[t]        = e * S;          // radial_emb
    crow[320 + t]  = qq * S;         // radial_q

    if (t < HDIM) {
        float a0 = 0.f, a1 = 0.f, a2 = 0.f;
#pragma unroll
        for (int g = 0; g < GDIM; ++g) {
            float mg = Mmat[(long long)i * 1024 + g * 64 + t];
            a0 += mg * sGV[0 * 16 + g];
            a1 += mg * sGV[1 * 16 + g];
            a2 += mg * sGV[2 * 16 + g];
        }
        crow[256 + t] = sqrtf(a0 * a0 + a1 * a1 + a2 * a2);  // vector_emb
        crow[576 + t] = 0.f;                                 // vector_q
    }
}

// ---------------------------------------------------------------------------
// Generic f32 GEMM, 64x64 tile, BK=16, 256 threads, 4x4 micro-tile.
//   C[m,n] = sum_k A[m,k] * (BT ? B[n,k] : B[k,n])
// MODE 0: plain store      MODE 1: +bias, gelu      MODE 2: +bias, remap (layer 3)
// Requires K % 16 == 0.
// ---------------------------------------------------------------------------
template<int MODE, bool BT>
__global__ void gemm64(const float* __restrict__ A,
                       const float* __restrict__ B,
                       const float* __restrict__ bias,
                       float* __restrict__ C,
                       int M, int N, int K) {
    __shared__ float As[64][17];
    __shared__ float Bs[16][65];
    int tx = threadIdx.x, ty = threadIdx.y;
    int tid = ty * 16 + tx;
    int bm = blockIdx.x, bn = blockIdx.y;
    float acc[4][4] = {};

    for (int kt = 0; kt < K; kt += 16) {
#pragma unroll
        for (int r = 0; r < 4; ++r) {
            int idx = tid + r * 256;
            int m = idx >> 4, k = idx & 15;
            int row = bm * 64 + m;
            As[m][k] = (row < M) ? A[(long long)row * K + kt + k] : 0.f;
        }
        if (BT) {
#pragma unroll
            for (int r = 0; r < 4; ++r) {
                int idx = tid + r * 256;
                int n = idx >> 4, k = idx & 15;
                int col = bn * 64 + n;
                Bs[k][n] = (col < N) ? B[(long long)col * K + kt + k] : 0.f;
            }
        } else {
#pragma unroll
            for (int r = 0; r < 4; ++r) {
                int idx = tid + r * 256;
                int k = idx >> 6, n = idx & 63;
                int col = bn * 64 + n;
                Bs[k][n] = (col < N) ? B[(long long)(kt + k) * N + col] : 0.f;
            }
        }
        __syncthreads();
#pragma unroll
        for (int kk = 0; kk < 16; ++kk) {
            float a[4], b[4];
#pragma unroll
            for (int i2 = 0; i2 < 4; ++i2) a[i2] = As[ty + i2 * 16][kk];
#pragma unroll
            for (int j = 0; j < 4; ++j) b[j] = Bs[kk][tx + j * 16];
#pragma unroll
            for (int i2 = 0; i2 < 4; ++i2)
#pragma unroll
                for (int j = 0; j < 4; ++j)
                    acc[i2][j] += a[i2] * b[j];
        }
        __syncthreads();
    }

#pragma unroll
    for (int i2 = 0; i2 < 4; ++i2) {
        int row = bm * 64 + ty + i2 * 16;
        if (row >= M) continue;
#pragma unroll
        for (int j = 0; j < 4; ++j) {
            int col = bn * 64 + tx + j * 16;
            if (col >= N) continue;
            float v = acc[i2][j];
            if (MODE == 0) {
                C[(long long)row * N + col] = v;
            } else if (MODE == 1) {
                v += bias[col];
                C[(long long)row * N + col] = gelu_exact(v);
            } else {
                v += bias[col];
                // out columns: 0 -> delta_q, 1 -> f, 2.. -> delta_a
                if (col == 0)      C[2560000 + row] = v;
                else if (col == 1) C[2570000 + row] = v;
                else               C[(long long)row * 256 + (col - 2)] = v;
            }
        }
    }
}

extern "C" void kernel_launch(void* const* d_in, const int* in_sizes, int n_in,
                              void* d_out, int out_size, void* d_ws, size_t ws_size,
                              hipStream_t stream) {
    const float* emb  = (const float*)d_in[0];
    const float* q    = (const float*)d_in[1];
    const int*   pidx = (const int*)d_in[2];
    const float* gs   = (const float*)d_in[3];
    const float* gv   = (const float*)d_in[4];
    const float* agh  = (const float*)d_in[5];
    const float* W_gs = (const float*)d_in[6];
    const float* W1   = (const float*)d_in[7];
    const float* b1   = (const float*)d_in[8];
    const float* W2   = (const float*)d_in[9];
    const float* b2   = (const float*)d_in[10];
    const float* W3   = (const float*)d_in[11];
    const float* b3   = (const float*)d_in[12];
    float* out = (float*)d_out;
    float* ws  = (float*)d_ws;

    // Workspace layout (floats). h1/h2 alias Mmat (free after build_combined).
    float* Gs_sum = ws;                    //    160,000
    float* GV_sum = ws + 160000;           //    480,000
    float* Mmat   = ws + 640000;           // 10,240,000  (N_ATOMS x 1024)
    float* comb   = ws + 10880000;         //  6,400,000  (N_ATOMS x 640)
    float* h1     = ws + 640000;           //  2,560,000  (aliases Mmat)
    float* h2     = ws + 640000 + 2560000; //  2,560,000  (aliases Mmat)
    // Peak usage: 17,280,000 floats = 69.1 MB

    const int* idx_j = pidx + N_PAIRS;

    // Zero the scatter accumulators.
    hipMemsetAsync(ws, 0, 640000 * sizeof(float), stream);

    {   // Segment-sums of gs and gv over pairs.
        long long total = (long long)N_PAIRS * 64;
        int blocks = (int)((total + 255) / 256);
        scatter_kernel<<<blocks, 256, 0, stream>>>(idx_j, gs, gv, Gs_sum, GV_sum);
    }
    {   // M = emb @ agh  : (10000 x 256) @ (256 x 1024)
        dim3 grid((N_ATOMS + 63) / 64, 1024 / 64);
        gemm64<0, false><<<grid, dim3(16, 16), 0, stream>>>(emb, agh, nullptr, Mmat,
                                                            N_ATOMS, 1024, FDIM);
    }
    // combined = [emb*S | norm_d(M x GV_sum) | q*S | 0]
    build_combined<<<N_ATOMS, 256, 0, stream>>>(emb, q, W_gs, Gs_sum, GV_sum, Mmat, comb);
    {   // MLP layer 1: h1 = gelu(comb @ W1.T + b1)
        dim3 grid((N_ATOMS + 63) / 64, HIDDIM / 64);
        gemm64<1, true><<<grid, dim3(16, 16), 0, stream>>>(comb, W1, b1, h1,
                                                           N_ATOMS, HIDDIM, MLP_IN);
        // MLP layer 2: h2 = gelu(h1 @ W2.T + b2)
        gemm64<1, true><<<grid, dim3(16, 16), 0, stream>>>(h1, W2, b2, h2,
                                                           N_ATOMS, HIDDIM, HIDDIM);
    }
    {   // MLP layer 3 + output remap: (delta_a | delta_q | f)
        dim3 grid((N_ATOMS + 63) / 64, (MLP_OUT + 63) / 64);
        gemm64<2, true><<<grid, dim3(16, 16), 0, stream>>>(h2, W3, b3, out,
                                                           N_ATOMS, MLP_OUT, HIDDIM);
    }
}

// Round 2
// 185.244 us; speedup vs baseline: 2.1725x; 2.1725x over previous
//
#include <hip/hip_runtime.h>
#include <hip/hip_bf16.h>
#include <math.h>

#define N_ATOMS 10000
#define N_PAIRS 160000
#define FDIM 256
#define GDIM 16
#define HDIM 64
#define HIDDIM 256
#define MLP_IN 640
#define MLP_OUT 258

typedef __attribute__((ext_vector_type(8))) short short8;
typedef __attribute__((ext_vector_type(4))) float f32x4;

__device__ __forceinline__ float gelu_exact(float x) {
    return 0.5f * x * (1.0f + erff(x * 0.70710678118654752f));
}

// ---------------------------------------------------------------------------
// Scatter: Gs_sum[i,g]  += gs[p,g]   (16 floats/pair)
//          GV_sum[i,d,g]+= gv[p,d,g] (48 floats/pair)
// ---------------------------------------------------------------------------
__global__ void scatter_kernel(const int* __restrict__ idx_j,
                               const float* __restrict__ gs,
                               const float* __restrict__ gv,
                               float* __restrict__ Gs_sum,
                               float* __restrict__ GV_sum) {
    long long tid = (long long)blockIdx.x * blockDim.x + threadIdx.x;
    if (tid >= (long long)N_PAIRS * 64) return;
    int p = (int)(tid >> 6);
    int e = (int)(tid & 63);
    int i = idx_j[p];
    if (e < GDIM) {
        atomicAdd(&Gs_sum[i * GDIM + e], gs[p * GDIM + e]);
    } else {
        int e2 = e - GDIM;
        atomicAdd(&GV_sum[i * 48 + e2], gv[p * 48 + e2]);
    }
}

// ---------------------------------------------------------------------------
// Prep: f32 -> bf16 conversions + agh transpose + W3 pad, one flat kernel.
// Regions (element counts):
//   [0, 2560000)              embB[i]   = bf(emb[i])
//   [+163840)                 W1b[i]    = bf(W1[i])          (256x640 [n][k])
//   [+65536)                  W2b[i]    = bf(W2[i])          (256x256 [n][k])
//   [+262144)                 aghT[n*256+k] = bf(agh[k*1024+n])   (1024x256)
//   [+81920)                  W3b[n*256+k]  = n<258 ? bf(W3[n*256+k]) : 0
// ---------------------------------------------------------------------------
#define PREP_TOTAL (2560000 + 163840 + 65536 + 262144 + 81920)
__global__ void prep_kernel(const float* __restrict__ emb,
                            const float* __restrict__ W1,
                            const float* __restrict__ W2,
                            const float* __restrict__ agh,
                            const float* __restrict__ W3,
                            __hip_bfloat16* __restrict__ embB,
                            __hip_bfloat16* __restrict__ W1b,
                            __hip_bfloat16* __restrict__ W2b,
                            __hip_bfloat16* __restrict__ aghT,
                            __hip_bfloat16* __restrict__ W3b) {
    int tid = blockIdx.x * blockDim.x + threadIdx.x;
    if (tid >= PREP_TOTAL) return;
    int j = tid;
    if (j < 2560000) { embB[j] = __float2bfloat16(emb[j]); return; }
    j -= 2560000;
    if (j < 163840) { W1b[j] = __float2bfloat16(W1[j]); return; }
    j -= 163840;
    if (j < 65536) { W2b[j] = __float2bfloat16(W2[j]); return; }
    j -= 65536;
    if (j < 262144) {
        int n = j >> 8, k = j & 255;
        aghT[j] = __float2bfloat16(agh[k * 1024 + n]);
        return;
    }
    j -= 262144;
    {
        int n = j >> 8, k = j & 255;
        W3b[j] = (n < MLP_OUT) ? __float2bfloat16(W3[n * 256 + k]) : __float2bfloat16(0.f);
    }
}

// ---------------------------------------------------------------------------
// bf16 MFMA GEMM: C[M,N] = A[M,K] @ B[N,K]^T, f32 accumulate.
// Block: 256 thr = 4 waves; block tile 128x64; wave tile 32x64 (2x4 frags).
// No LDS: direct 16B global fragment loads (operands are L2-resident).
// MODE 0: store bf16          MODE 1: +bias, gelu, store bf16
// MODE 2: +bias, remap to (delta_a | delta_q | f) in f32 out
// ---------------------------------------------------------------------------
template<int MODE, int M, int N, int K>
__global__ __launch_bounds__(256) void gemm_mfma(const short* __restrict__ A,
                                                 const short* __restrict__ B,
                                                 const float* __restrict__ bias,
                                                 void* __restrict__ Cout) {
    int lane = threadIdx.x & 63;
    int wave = threadIdx.x >> 6;
    int m0 = blockIdx.x * 128 + wave * 32;
    int n0 = blockIdx.y * 64;
    int lr = lane & 15;
    int koff0 = (lane >> 4) * 8;

    f32x4 acc[2][4] = {};
    const short8 zero8 = {};

    const short* A0 = A + (long long)(m0 + lr) * K + koff0;
    const short* A1 = A + (long long)(m0 + 16 + lr) * K + koff0;
    const short* Bb = B + (long long)(n0 + lr) * K + koff0;
    bool ok0 = (m0 + lr) < M;
    bool ok1 = (m0 + 16 + lr) < M;

#pragma unroll 2
    for (int ks = 0; ks < K; ks += 32) {
        short8 a0 = ok0 ? *(const short8*)(A0 + ks) : zero8;
        short8 a1 = ok1 ? *(const short8*)(A1 + ks) : zero8;
        short8 b0 = *(const short8*)(Bb + ks);
        short8 b1 = *(const short8*)(Bb + 16 * K + ks);
        short8 b2 = *(const short8*)(Bb + 32 * K + ks);
        short8 b3 = *(const short8*)(Bb + 48 * K + ks);
        acc[0][0] = __builtin_amdgcn_mfma_f32_16x16x32_bf16(a0, b0, acc[0][0], 0, 0, 0);
        acc[0][1] = __builtin_amdgcn_mfma_f32_16x16x32_bf16(a0, b1, acc[0][1], 0, 0, 0);
        acc[0][2] = __builtin_amdgcn_mfma_f32_16x16x32_bf16(a0, b2, acc[0][2], 0, 0, 0);
        acc[0][3] = __builtin_amdgcn_mfma_f32_16x16x32_bf16(a0, b3, acc[0][3], 0, 0, 0);
        acc[1][0] = __builtin_amdgcn_mfma_f32_16x16x32_bf16(a1, b0, acc[1][0], 0, 0, 0);
        acc[1][1] = __builtin_amdgcn_mfma_f32_16x16x32_bf16(a1, b1, acc[1][1], 0, 0, 0);
        acc[1][2] = __builtin_amdgcn_mfma_f32_16x16x32_bf16(a1, b2, acc[1][2], 0, 0, 0);
        acc[1][3] = __builtin_amdgcn_mfma_f32_16x16x32_bf16(a1, b3, acc[1][3], 0, 0, 0);
    }

    // C/D layout: col = lane&15, row = (lane>>4)*4 + r   [verified m89/m91]
    float* outp = (float*)Cout;
    __hip_bfloat16* outb = (__hip_bfloat16*)Cout;
    int rbase = (lane >> 4) * 4;
#pragma unroll
    for (int f2 = 0; f2 < 2; ++f2) {
#pragma unroll
        for (int g = 0; g < 4; ++g) {
            int col = n0 + g * 16 + lr;
            if (MODE == 2 && col >= MLP_OUT) continue;
#pragma unroll
            for (int r = 0; r < 4; ++r) {
                int row = m0 + f2 * 16 + rbase + r;
                if (row >= M) continue;
                float v = acc[f2][g][r];
                if (MODE == 0) {
                    outb[(long long)row * N + col] = __float2bfloat16(v);
                } else if (MODE == 1) {
                    v += bias[col];
                    outb[(long long)row * N + col] = __float2bfloat16(gelu_exact(v));
                } else {
                    v += bias[col];
                    if (col == 0)      outp[2560000 + row] = v;
                    else if (col == 1) outp[2570000 + row] = v;
                    else               outp[(long long)row * 256 + (col - 2)] = v;
                }
            }
        }
    }
}

// ---------------------------------------------------------------------------
// Build "combined" (N x 640 bf16): [radial_emb | vector_emb | radial_q | 0]
// One block (256 threads) per atom. Mmat is bf16 (10000 x 1024, n = g*64+h).
// ---------------------------------------------------------------------------
__global__ void build_combined(const float* __restrict__ emb,
                               const float* __restrict__ q,
                               const float* __restrict__ W_gs,
                               const float* __restrict__ Gs_sum,
                               const float* __restrict__ GV_sum,
                               const __hip_bfloat16* __restrict__ Mmat,
                               __hip_bfloat16* __restrict__ combined) {
    __shared__ float sW[FDIM * 17];
    __shared__ float sG[GDIM];
    __shared__ float sGV[48];
    int i = blockIdx.x;
    int t = threadIdx.x;

    for (int j = t; j < FDIM * GDIM; j += 256) {
        int f = j >> 4, g = j & 15;
        sW[f * 17 + g] = W_gs[j];
    }
    if (t < GDIM) sG[t] = Gs_sum[i * GDIM + t];
    if (t < 48)  sGV[t] = GV_sum[i * 48 + t];
    __syncthreads();

    float S = 0.f;
#pragma unroll
    for (int g = 0; g < GDIM; ++g) S += sG[g] * sW[t * 17 + g];

    float e  = emb[(long long)i * FDIM + t];
    float qq = q[i];
    __hip_bfloat16* crow = combined + (long long)i * MLP_IN;
    crow[t]       = __float2bfloat16(e * S);
    crow[320 + t] = __float2bfloat16(qq * S);

    if (t < HDIM) {
        float a0 = 0.f, a1 = 0.f, a2 = 0.f;
#pragma unroll
        for (int g = 0; g < GDIM; ++g) {
            float mg = __bfloat162float(Mmat[(long long)i * 1024 + g * 64 + t]);
            a0 += mg * sGV[0 * 16 + g];
            a1 += mg * sGV[1 * 16 + g];
            a2 += mg * sGV[2 * 16 + g];
        }
        crow[256 + t] = __float2bfloat16(sqrtf(a0 * a0 + a1 * a1 + a2 * a2));
        crow[576 + t] = __float2bfloat16(0.f);
    }
}

extern "C" void kernel_launch(void* const* d_in, const int* in_sizes, int n_in,
                              void* d_out, int out_size, void* d_ws, size_t ws_size,
                              hipStream_t stream) {
    const float* emb  = (const float*)d_in[0];
    const float* q    = (const float*)d_in[1];
    const int*   pidx = (const int*)d_in[2];
    const float* gs   = (const float*)d_in[3];
    const float* gv   = (const float*)d_in[4];
    const float* agh  = (const float*)d_in[5];
    const float* W_gs = (const float*)d_in[6];
    const float* W1   = (const float*)d_in[7];
    const float* b1   = (const float*)d_in[8];
    const float* W2   = (const float*)d_in[9];
    const float* b2   = (const float*)d_in[10];
    const float* W3   = (const float*)d_in[11];
    const float* b3   = (const float*)d_in[12];
    float* out = (float*)d_out;
    float* ws  = (float*)d_ws;

    // Workspace layout (float offsets; bf16 buffers take n/2 floats).
    float* Gs_sum = ws;                                   // 160,000 f
    float* GV_sum = ws + 160000;                          // 480,000 f
    __hip_bfloat16* Mmat = (__hip_bfloat16*)(ws + 640000);     // 10000x1024 bf16 (5,120,000 f)
    __hip_bfloat16* embB = (__hip_bfloat16*)(ws + 5760000);    // 10000x256  bf16 (1,280,000 f)
    __hip_bfloat16* aghT = (__hip_bfloat16*)(ws + 7040000);    // 1024x256   bf16 (131,072 f)
    __hip_bfloat16* W1b  = (__hip_bfloat16*)(ws + 7171072);    // 256x640    bf16 (81,920 f)
    __hip_bfloat16* W2b  = (__hip_bfloat16*)(ws + 7252992);    // 256x256    bf16 (32,768 f)
    __hip_bfloat16* W3b  = (__hip_bfloat16*)(ws + 7285760);    // 320x256    bf16 (40,960 f)
    __hip_bfloat16* comb = (__hip_bfloat16*)(ws + 7326720);    // 10000x640  bf16 (3,200,000 f)
    __hip_bfloat16* h1b  = (__hip_bfloat16*)(ws + 10526720);   // 10000x256  bf16 (1,280,000 f)
    __hip_bfloat16* h2b  = (__hip_bfloat16*)(ws + 11806720);   // 10000x256  bf16 (1,280,000 f)
    // Total: 13,086,720 floats = 52.3 MB

    const int* idx_j = pidx + N_PAIRS;

    hipMemsetAsync(ws, 0, 640000 * sizeof(float), stream);

    {   // bf16 conversions + agh transpose + W3 pad
        int blocks = (PREP_TOTAL + 255) / 256;
        prep_kernel<<<blocks, 256, 0, stream>>>(emb, W1, W2, agh, W3,
                                                embB, W1b, W2b, aghT, W3b);
    }
    {   // segment-sums of gs, gv
        long long total = (long long)N_PAIRS * 64;
        int blocks = (int)((total + 255) / 256);
        scatter_kernel<<<blocks, 256, 0, stream>>>(idx_j, gs, gv, Gs_sum, GV_sum);
    }
    {   // Mmat = embB @ aghT^T : (10000x256)@(256x1024) -> bf16
        dim3 grid((N_ATOMS + 127) / 128, 1024 / 64);
        gemm_mfma<0, N_ATOMS, 1024, 256><<<grid, 256, 0, stream>>>(
            (const short*)embB, (const short*)aghT, nullptr, Mmat);
    }
    build_combined<<<N_ATOMS, 256, 0, stream>>>(emb, q, W_gs, Gs_sum, GV_sum, Mmat, comb);
    {   // MLP1: h1 = gelu(comb @ W1^T + b1)
        dim3 grid((N_ATOMS + 127) / 128, HIDDIM / 64);
        gemm_mfma<1, N_ATOMS, HIDDIM, MLP_IN><<<grid, 256, 0, stream>>>(
            (const short*)comb, (const short*)W1b, b1, h1b);
        // MLP2: h2 = gelu(h1 @ W2^T + b2)
        gemm_mfma<1, N_ATOMS, HIDDIM, HIDDIM><<<grid, 256, 0, stream>>>(
            (const short*)h1b, (const short*)W2b, b2, h2b);
    }
    {   // MLP3 + remap
        dim3 grid((N_ATOMS + 127) / 128, 320 / 64);
        gemm_mfma<2, N_ATOMS, 320, HIDDIM><<<grid, 256, 0, stream>>>(
            (const short*)h2b, (const short*)W3b, b3, out);
    }
}